// Round 6
// baseline (274.978 us; speedup 1.0000x reference)
//
#include <hip/hip_runtime.h>
#include <hip/hip_bf16.h>

#define H 1024
#define T 2048
#define B 32
#define BM 128        // rows per block
#define BKC 64        // k per LDS chunk
#define NCHUNK 16     // H / BKC
#define NCOLT 2       // column tiles
#define BCOLS 512     // cols per block

typedef __attribute__((ext_vector_type(8))) __bf16 bf16x8;
typedef __attribute__((ext_vector_type(16))) float f32x16;
typedef __attribute__((ext_vector_type(8))) unsigned short u16x8;

__device__ __forceinline__ unsigned short f2bf(float f) {
    unsigned int x = __float_as_uint(f);
    x += 0x7fffu + ((x >> 16) & 1u);
    return (unsigned short)(x >> 16);
}

__device__ __forceinline__ float fast_tanh(float x) {
    float t = __expf(2.0f * x);
    return 1.0f - 2.0f * __builtin_amdgcn_rcpf(t + 1.0f);
}

// Pack W2 = W[:, H:2H] into bf16, layout Wp[kg][n][8] (kg = k>>3), 16B per (kg,n)
__global__ __launch_bounds__(256) void prep_w_kernel(const float* __restrict__ W,
                                                     unsigned short* __restrict__ Wp) {
    int gid = blockIdx.x * 256 + threadIdx.x;   // 131072 total
    int n = gid & (H - 1);
    int kg = gid >> 10;                          // 0..127
    const float* srcp = W + (size_t)n * (2 * H) + H + kg * 8;
    float4 f0 = *(const float4*)(srcp);
    float4 f1 = *(const float4*)(srcp + 4);
    u16x8 o;
    o[0] = f2bf(f0.x); o[1] = f2bf(f0.y); o[2] = f2bf(f0.z); o[3] = f2bf(f0.w);
    o[4] = f2bf(f1.x); o[5] = f2bf(f1.y); o[6] = f2bf(f1.z); o[7] = f2bf(f1.w);
    *(u16x8*)(Wp + (size_t)gid * 8) = o;
}

// hp[b][h] = sum_d hidden[b][d] * W[h][d] + bias[h]   (fp32, exact part)
__global__ __launch_bounds__(128) void prep_hp_kernel(const float* __restrict__ hidden,
                                                      const float* __restrict__ W,
                                                      const float* __restrict__ bias,
                                                      float* __restrict__ hp) {
    int b = blockIdx.y;
    int h = blockIdx.x * 128 + threadIdx.x;
    const float* hid = hidden + (size_t)b * H;
    const float* wr = W + (size_t)h * (2 * H);
    float acc = 0.f;
    for (int d = 0; d < H; d += 4) {
        float4 wv = *(const float4*)(wr + d);
        float4 hv = *(const float4*)(hid + d);
        acc += wv.x * hv.x + wv.y * hv.y + wv.z * hv.z + wv.w * hv.w;
    }
    hp[(size_t)b * H + h] = acc + bias[h];
}

#define MFMA32(A, Bv, C) __builtin_amdgcn_mfma_f32_32x32x16_bf16(A, Bv, C, 0, 0, 0)

// Block = (128-row t-tile, 512-col tile, b). 16 waves; wave owns 32 cols x 128 rows.
// acc = f32x16[4] (64 AGPR). LDS A-chunk: 16B unit at kslot*2048 + ((row^kslot)<<4),
// kslot 0..7 (k-group of 8 within 64-k chunk), row 0..127.  (zero-conflict layout, per R2/R3)
__global__ __launch_bounds__(1024, 4) void energy_kernel(const float* __restrict__ enc,
                                                         const float* __restrict__ hp,
                                                         const float* __restrict__ vvec,
                                                         const unsigned short* __restrict__ Wp,
                                                         float* __restrict__ sc_part) {
    __shared__ __align__(16) unsigned short Abuf[2][BM * BKC];  // 2 x 16 KB
    __shared__ float scpart[16][BM];                            // 8 KB

    const int tid = threadIdx.x;
    const int b = blockIdx.z;
    const int t0 = blockIdx.x * BM;
    const int c0 = blockIdx.y * BCOLS;
    const int wave = tid >> 6;
    const int lane = tid & 63;
    const int l31 = lane & 31;
    const int hi = lane >> 5;

    // staging: kslot = tid&7 (8 consecutive k), row = tid>>3 (0..127); 32B global read
    const int st_ks = tid & 7;
    const int st_row = tid >> 3;
    const float* st_src = enc + ((size_t)b * T + t0 + st_row) * H + st_ks * 8;
    char* Ab0 = (char*)&Abuf[0][0];
    char* st_dst = Ab0 + st_ks * 2048 + (((st_row ^ st_ks)) << 4);

    // B stream: per k-step it (0..63), kg = it*2 + hi; col = c0 + wave*32 + l31
    const unsigned short* wp_base = Wp + (size_t)(c0 + wave * 32 + l31) * 8 + (size_t)hi * (H * 8);

    f32x16 acc[4];
#pragma unroll
    for (int rg = 0; rg < 4; ++rg)
#pragma unroll
        for (int i = 0; i < 16; ++i) acc[rg][i] = 0.f;

    // row bases for a-frags (per 32-row group)
    const int rv0 = 0 * 32 + l31;
    const int rv1 = 1 * 32 + l31;
    const int rv2 = 2 * 32 + l31;
    const int rv3 = 3 * 32 + l31;

    // ---- prologue: stage chunk 0; preload B it=0,1 (depth-2 rolling) ----
    {
        float4 f0 = *(const float4*)(st_src);
        float4 f1 = *(const float4*)(st_src + 4);
        u16x8 o;
        o[0] = f2bf(f0.x); o[1] = f2bf(f0.y); o[2] = f2bf(f0.z); o[3] = f2bf(f0.w);
        o[4] = f2bf(f1.x); o[5] = f2bf(f1.y); o[6] = f2bf(f1.z); o[7] = f2bf(f1.w);
        *(u16x8*)st_dst = o;
    }
    bf16x8 bfA = *(const bf16x8*)(wp_base);                       // it=0
    bf16x8 bfB = *(const bf16x8*)(wp_base + (size_t)1 * (H * 16)); // it=1
    __syncthreads();

    // NOTE: rolling invariant -- at STEP(KI) of chunk j, BF holds it = 4j+KI and we
    // reload it+2. The reloads for the FINAL chunk's steps 2,3 happen during its own
    // steps 0,1, so the guard must be per-step (nit < 64), not per-chunk (R5 bug).
#define STEP(KI, BF)                                                          \
    {                                                                          \
        const int kslot = (KI) * 2 + hi;                                       \
        const char* ap = Ab + kslot * 2048;                                    \
        bf16x8 a0 = *(const bf16x8*)(ap + ((rv0 ^ kslot) << 4));               \
        bf16x8 a1 = *(const bf16x8*)(ap + ((rv1 ^ kslot) << 4));               \
        bf16x8 a2 = *(const bf16x8*)(ap + ((rv2 ^ kslot) << 4));               \
        bf16x8 a3 = *(const bf16x8*)(ap + ((rv3 ^ kslot) << 4));               \
        acc[0] = MFMA32(a0, BF, acc[0]);                                       \
        acc[1] = MFMA32(a1, BF, acc[1]);                                       \
        acc[2] = MFMA32(a2, BF, acc[2]);                                       \
        acc[3] = MFMA32(a3, BF, acc[3]);                                       \
        const int nit = j * 4 + (KI) + 2;                                      \
        if (nit < 64) BF = *(const bf16x8*)(wp_base + (size_t)nit * (H * 16)); \
    }

    for (int j = 0; j < NCHUNK; ++j) {
        // issue A prefetch for chunk j+1 early
        float4 f0, f1;
        const bool pfA = (j < NCHUNK - 1);
        if (pfA) {
            const float* p = st_src + (j + 1) * BKC;
            f0 = *(const float4*)(p);
            f1 = *(const float4*)(p + 4);
        }
        const char* Ab = Ab0 + (j & 1) * 16384;
        STEP(0, bfA)
        STEP(1, bfB)
        STEP(2, bfA)
        STEP(3, bfB)
        if (pfA) {
            u16x8 o;
            o[0] = f2bf(f0.x); o[1] = f2bf(f0.y); o[2] = f2bf(f0.z); o[3] = f2bf(f0.w);
            o[4] = f2bf(f1.x); o[5] = f2bf(f1.y); o[6] = f2bf(f1.z); o[7] = f2bf(f1.w);
            *(u16x8*)(st_dst + ((j + 1) & 1) * 16384) = o;
        }
        __syncthreads();
    }
#undef STEP

    // ---- fused epilogue: tanh + v-dot over this wave's 32 cols ----
    const size_t bH = (size_t)b * H;
    const int col = c0 + wave * 32 + l31;
    const float hpv = hp[bH + col];
    const float vv = vvec[col];
    float psc[4][16];
#pragma unroll
    for (int rg = 0; rg < 4; ++rg)
#pragma unroll
        for (int r = 0; r < 16; ++r)
            psc[rg][r] = vv * fast_tanh(acc[rg][r] + hpv);

#pragma unroll
    for (int rg = 0; rg < 4; ++rg)
#pragma unroll
        for (int r = 0; r < 16; ++r) {
            float s = psc[rg][r];
            s += __shfl_xor(s, 1);
            s += __shfl_xor(s, 2);
            s += __shfl_xor(s, 4);
            s += __shfl_xor(s, 8);
            s += __shfl_xor(s, 16);
            psc[rg][r] = s;
        }
    if (l31 == 0) {
#pragma unroll
        for (int rg = 0; rg < 4; ++rg)
#pragma unroll
            for (int r = 0; r < 16; ++r) {
                int m = rg * 32 + (r & 3) + 8 * (r >> 2) + 4 * hi;
                scpart[wave][m] = psc[rg][r];
            }
    }
    __syncthreads();
    if (tid < BM) {
        float s = 0.f;
#pragma unroll
        for (int w = 0; w < 16; ++w) s += scpart[w][tid];
        sc_part[((size_t)blockIdx.y * B + b) * T + t0 + tid] = s;
    }
}

__global__ __launch_bounds__(256) void softmax_kernel(const float* __restrict__ sc,
                                                      float* __restrict__ out) {
    int b = blockIdx.x;
    int tid = threadIdx.x;
    int wave = tid >> 6, lane = tid & 63;
    const float* row0 = sc + (size_t)b * T;
    const float* row1 = sc + ((size_t)B + b) * T;
    float vals[8];
    float m = -1e30f;
#pragma unroll
    for (int i = 0; i < 8; ++i) {
        int idx = tid + 256 * i;
        vals[i] = row0[idx] + row1[idx];
        m = fmaxf(m, vals[i]);
    }
#pragma unroll
    for (int s = 1; s < 64; s <<= 1) m = fmaxf(m, __shfl_xor(m, s));
    __shared__ float red[4];
    __shared__ float red2[4];
    if (lane == 0) red[wave] = m;
    __syncthreads();
    m = fmaxf(fmaxf(red[0], red[1]), fmaxf(red[2], red[3]));
    float sum = 0.f;
#pragma unroll
    for (int i = 0; i < 8; ++i) { vals[i] = expf(vals[i] - m); sum += vals[i]; }
#pragma unroll
    for (int s = 1; s < 64; s <<= 1) sum += __shfl_xor(sum, s);
    if (lane == 0) red2[wave] = sum;
    __syncthreads();
    sum = red2[0] + red2[1] + red2[2] + red2[3];
    float inv = 1.0f / sum;
#pragma unroll
    for (int i = 0; i < 8; ++i) out[(size_t)b * T + tid + 256 * i] = vals[i] * inv;
}

extern "C" void kernel_launch(void* const* d_in, const int* in_sizes, int n_in,
                              void* d_out, int out_size, void* d_ws, size_t ws_size,
                              hipStream_t stream) {
    (void)in_sizes; (void)n_in; (void)out_size; (void)ws_size;
    const float* hidden = (const float*)d_in[0];   // [1,B,H]
    const float* enc    = (const float*)d_in[1];   // [B,T,H]
    const float* W      = (const float*)d_in[2];   // [H,2H]
    const float* bias   = (const float*)d_in[3];   // [H]
    const float* v      = (const float*)d_in[4];   // [H]
    float* out = (float*)d_out;                    // [B,1,T]

    unsigned short* Wp = (unsigned short*)d_ws;                              // 2 MB
    float* hp = (float*)((char*)d_ws + 2 * 1024 * 1024);                     // 128 KB
    float* sc = (float*)((char*)d_ws + 2 * 1024 * 1024 + 128 * 1024);        // 512 KB (2 partials)

    prep_w_kernel<<<dim3(512), dim3(256), 0, stream>>>(W, Wp);
    prep_hp_kernel<<<dim3(8, B), dim3(128), 0, stream>>>(hidden, W, bias, hp);
    energy_kernel<<<dim3(T / BM, NCOLT, B), dim3(1024), 0, stream>>>(enc, hp, v, Wp, sc);
    softmax_kernel<<<dim3(B), dim3(256), 0, stream>>>(sc, out);
}

// Round 7
// 258.578 us; speedup vs baseline: 1.0634x; 1.0634x over previous
//
#include <hip/hip_runtime.h>
#include <hip/hip_bf16.h>

#define H 1024
#define T 2048
#define B 32
#define BM 128        // rows per block
#define BKC 64        // k per LDS chunk
#define NCHUNK 16     // H / BKC
#define NCOLT 4       // column tiles
#define BCOLS 256     // cols per block

typedef __attribute__((ext_vector_type(8))) __bf16 bf16x8;
typedef __attribute__((ext_vector_type(16))) float f32x16;
typedef __attribute__((ext_vector_type(8))) unsigned short u16x8;

__device__ __forceinline__ unsigned short f2bf(float f) {
    unsigned int x = __float_as_uint(f);
    x += 0x7fffu + ((x >> 16) & 1u);
    return (unsigned short)(x >> 16);
}

__device__ __forceinline__ float fast_tanh(float x) {
    float t = __expf(2.0f * x);
    return 1.0f - 2.0f * __builtin_amdgcn_rcpf(t + 1.0f);
}

// Pack W2 = W[:, H:2H] into bf16, layout Wp[kg][n][8] (kg = k>>3), 16B per (kg,n)
__global__ __launch_bounds__(256) void prep_w_kernel(const float* __restrict__ W,
                                                     unsigned short* __restrict__ Wp) {
    int gid = blockIdx.x * 256 + threadIdx.x;   // 131072 total
    int n = gid & (H - 1);
    int kg = gid >> 10;                          // 0..127
    const float* srcp = W + (size_t)n * (2 * H) + H + kg * 8;
    float4 f0 = *(const float4*)(srcp);
    float4 f1 = *(const float4*)(srcp + 4);
    u16x8 o;
    o[0] = f2bf(f0.x); o[1] = f2bf(f0.y); o[2] = f2bf(f0.z); o[3] = f2bf(f0.w);
    o[4] = f2bf(f1.x); o[5] = f2bf(f1.y); o[6] = f2bf(f1.z); o[7] = f2bf(f1.w);
    *(u16x8*)(Wp + (size_t)gid * 8) = o;
}

// hp[b][h] = sum_d hidden[b][d] * W[h][d] + bias[h]   (fp32, exact part)
__global__ __launch_bounds__(128) void prep_hp_kernel(const float* __restrict__ hidden,
                                                      const float* __restrict__ W,
                                                      const float* __restrict__ bias,
                                                      float* __restrict__ hp) {
    int b = blockIdx.y;
    int h = blockIdx.x * 128 + threadIdx.x;
    const float* hid = hidden + (size_t)b * H;
    const float* wr = W + (size_t)h * (2 * H);
    float acc = 0.f;
    for (int d = 0; d < H; d += 4) {
        float4 wv = *(const float4*)(wr + d);
        float4 hv = *(const float4*)(hid + d);
        acc += wv.x * hv.x + wv.y * hv.y + wv.z * hv.z + wv.w * hv.w;
    }
    hp[(size_t)b * H + h] = acc + bias[h];
}

#define MFMA32(A, Bv, C) __builtin_amdgcn_mfma_f32_32x32x16_bf16(A, Bv, C, 0, 0, 0)

// Block = (128-row t-tile, 256-col tile, b). 8 waves (512 thr) arranged 2 (row) x 4 (col);
// wave = 64 rows x 64 cols: per k-step 2 A-frag ds_reads + 2 B-frag L2 loads -> 4 MFMA.
// acc = f32x16[2][2] (64 AGPR). Two resident blocks/CU give cross-block pipe overlap.
// LDS A-chunk: 16B unit at kslot*2048 + ((row^kslot)<<4), kslot 0..7, row 0..127.
__global__ __launch_bounds__(512, 4) void energy_kernel(const float* __restrict__ enc,
                                                        const float* __restrict__ hp,
                                                        const float* __restrict__ vvec,
                                                        const unsigned short* __restrict__ Wp,
                                                        float* __restrict__ sc_part) {
    __shared__ __align__(16) unsigned short Abuf[2][BM * BKC];  // 2 x 16 KB
    __shared__ float scpart[8][BM];                             // 4 KB

    const int tid = threadIdx.x;
    const int b = blockIdx.z;
    const int t0 = blockIdx.x * BM;
    const int c0 = blockIdx.y * BCOLS;
    const int wave = tid >> 6;
    const int lane = tid & 63;
    const int l31 = lane & 31;
    const int hi = lane >> 5;
    const int wr = wave >> 2;     // 0..1 row-half
    const int wc = wave & 3;      // 0..3 col-group

    // staging: row = tid>>2 (0..127), kquad = tid&3 (16 k each -> kslots 2q, 2q+1)
    const int st_row = tid >> 2;
    const int st_kq = tid & 3;
    const int ks0 = st_kq * 2, ks1 = ks0 + 1;
    const float* st_src = enc + ((size_t)b * T + t0 + st_row) * H + st_kq * 16;
    char* Ab0 = (char*)&Abuf[0][0];
    char* st_d0 = Ab0 + ks0 * 2048 + (((st_row ^ ks0)) << 4);
    char* st_d1 = Ab0 + ks1 * 2048 + (((st_row ^ ks1)) << 4);

    // B stream: per k-step it (0..63), kg = it*2 + hi; cols wc*64 + {0,32} + l31
    const unsigned short* wp_base = Wp + (size_t)(c0 + wc * 64 + l31) * 8 + (size_t)hi * (H * 8);

    f32x16 acc00, acc01, acc10, acc11;
#pragma unroll
    for (int i = 0; i < 16; ++i) { acc00[i] = 0.f; acc01[i] = 0.f; acc10[i] = 0.f; acc11[i] = 0.f; }

    const int rv0 = wr * 64 + l31;        // row bases for the 2 a-frags
    const int rv1 = wr * 64 + 32 + l31;

    // ---- prologue: stage chunk 0; preload B it=0,1 (depth-2 rolling, 2 cg frags each) ----
    {
        float4 f0 = *(const float4*)(st_src);
        float4 f1 = *(const float4*)(st_src + 4);
        float4 f2 = *(const float4*)(st_src + 8);
        float4 f3 = *(const float4*)(st_src + 12);
        u16x8 o0, o1;
        o0[0] = f2bf(f0.x); o0[1] = f2bf(f0.y); o0[2] = f2bf(f0.z); o0[3] = f2bf(f0.w);
        o0[4] = f2bf(f1.x); o0[5] = f2bf(f1.y); o0[6] = f2bf(f1.z); o0[7] = f2bf(f1.w);
        o1[0] = f2bf(f2.x); o1[1] = f2bf(f2.y); o1[2] = f2bf(f2.z); o1[3] = f2bf(f2.w);
        o1[4] = f2bf(f3.x); o1[5] = f2bf(f3.y); o1[6] = f2bf(f3.z); o1[7] = f2bf(f3.w);
        *(u16x8*)st_d0 = o0;
        *(u16x8*)st_d1 = o1;
    }
    bf16x8 bA0 = *(const bf16x8*)(wp_base);                            // it=0, cg=0
    bf16x8 bA1 = *(const bf16x8*)(wp_base + 256);                      // it=0, cg=1
    bf16x8 bB0 = *(const bf16x8*)(wp_base + (size_t)1 * (H * 16));     // it=1, cg=0
    bf16x8 bB1 = *(const bf16x8*)(wp_base + (size_t)1 * (H * 16) + 256);
    __syncthreads();

    // Rolling invariant: at STEP(KI) of chunk j, (C0,C1) hold it = 4j+KI; reload it+2
    // into the same slot. Guard is PER-STEP (nit < 64) -- final chunk's steps 2,3 get
    // their B during its own steps 0,1 (R5 lesson).
#define STEP(KI, C0, C1)                                                       \
    {                                                                          \
        const int kslot = (KI) * 2 + hi;                                       \
        const char* ap = Ab + kslot * 2048;                                    \
        bf16x8 a0 = *(const bf16x8*)(ap + ((rv0 ^ kslot) << 4));               \
        bf16x8 a1 = *(const bf16x8*)(ap + ((rv1 ^ kslot) << 4));               \
        __builtin_amdgcn_s_setprio(1);                                         \
        acc00 = MFMA32(a0, C0, acc00);                                         \
        acc01 = MFMA32(a0, C1, acc01);                                         \
        acc10 = MFMA32(a1, C0, acc10);                                         \
        acc11 = MFMA32(a1, C1, acc11);                                         \
        __builtin_amdgcn_s_setprio(0);                                         \
        const int nit = j * 4 + (KI) + 2;                                      \
        if (nit < 64) {                                                        \
            const unsigned short* bp = wp_base + (size_t)nit * (H * 16);       \
            C0 = *(const bf16x8*)(bp);                                         \
            C1 = *(const bf16x8*)(bp + 256);                                   \
        }                                                                      \
    }

    for (int j = 0; j < NCHUNK; ++j) {
        // issue A prefetch for chunk j+1 early (T14 async-split: load-early, write-late)
        float4 f0, f1, f2, f3;
        const bool pfA = (j < NCHUNK - 1);
        if (pfA) {
            const float* p = st_src + (j + 1) * BKC;
            f0 = *(const float4*)(p);
            f1 = *(const float4*)(p + 4);
            f2 = *(const float4*)(p + 8);
            f3 = *(const float4*)(p + 12);
        }
        const char* Ab = Ab0 + (j & 1) * 16384;
        STEP(0, bA0, bA1)
        STEP(1, bB0, bB1)
        STEP(2, bA0, bA1)
        STEP(3, bB0, bB1)
        if (pfA) {
            u16x8 o0, o1;
            o0[0] = f2bf(f0.x); o0[1] = f2bf(f0.y); o0[2] = f2bf(f0.z); o0[3] = f2bf(f0.w);
            o0[4] = f2bf(f1.x); o0[5] = f2bf(f1.y); o0[6] = f2bf(f1.z); o0[7] = f2bf(f1.w);
            o1[0] = f2bf(f2.x); o1[1] = f2bf(f2.y); o1[2] = f2bf(f2.z); o1[3] = f2bf(f2.w);
            o1[4] = f2bf(f3.x); o1[5] = f2bf(f3.y); o1[6] = f2bf(f3.z); o1[7] = f2bf(f3.w);
            char* d0 = st_d0 + ((j + 1) & 1) * 16384;
            char* d1 = st_d1 + ((j + 1) & 1) * 16384;
            *(u16x8*)d0 = o0;
            *(u16x8*)d1 = o1;
        }
        __syncthreads();
    }
#undef STEP

    // ---- fused epilogue: tanh + v-dot over this wave's 64 cols ----
    const size_t bH = (size_t)b * H;
    const int col0 = c0 + wc * 64 + l31;
    const int col1 = col0 + 32;
    const float hp0 = hp[bH + col0], hp1 = hp[bH + col1];
    const float v0 = vvec[col0], v1 = vvec[col1];
    float psc[2][16];
#pragma unroll
    for (int r = 0; r < 16; ++r) {
        psc[0][r] = v0 * fast_tanh(acc00[r] + hp0) + v1 * fast_tanh(acc01[r] + hp1);
        psc[1][r] = v0 * fast_tanh(acc10[r] + hp0) + v1 * fast_tanh(acc11[r] + hp1);
    }

#pragma unroll
    for (int rg = 0; rg < 2; ++rg)
#pragma unroll
        for (int r = 0; r < 16; ++r) {
            float s = psc[rg][r];
            s += __shfl_xor(s, 1);
            s += __shfl_xor(s, 2);
            s += __shfl_xor(s, 4);
            s += __shfl_xor(s, 8);
            s += __shfl_xor(s, 16);
            psc[rg][r] = s;
        }
    if (l31 == 0) {
#pragma unroll
        for (int rg = 0; rg < 2; ++rg)
#pragma unroll
            for (int r = 0; r < 16; ++r) {
                int m = wr * 64 + rg * 32 + (r & 3) + 8 * (r >> 2) + 4 * hi;
                scpart[wave][m] = psc[rg][r];
            }
    }
    __syncthreads();
    if (tid < BM) {
        const int wbase = (tid >> 6) * 4;   // waves with this row-half
        float s = scpart[wbase][tid] + scpart[wbase + 1][tid] +
                  scpart[wbase + 2][tid] + scpart[wbase + 3][tid];
        sc_part[((size_t)blockIdx.y * B + b) * T + t0 + tid] = s;
    }
}

__global__ __launch_bounds__(256) void softmax_kernel(const float* __restrict__ sc,
                                                      float* __restrict__ out) {
    int b = blockIdx.x;
    int tid = threadIdx.x;
    int wave = tid >> 6, lane = tid & 63;
    const float* r0 = sc + (size_t)b * T;
    const float* r1 = sc + ((size_t)B + b) * T;
    const float* r2 = sc + ((size_t)2 * B + b) * T;
    const float* r3 = sc + ((size_t)3 * B + b) * T;
    float vals[8];
    float m = -1e30f;
#pragma unroll
    for (int i = 0; i < 8; ++i) {
        int idx = tid + 256 * i;
        vals[i] = (r0[idx] + r1[idx]) + (r2[idx] + r3[idx]);
        m = fmaxf(m, vals[i]);
    }
#pragma unroll
    for (int s = 1; s < 64; s <<= 1) m = fmaxf(m, __shfl_xor(m, s));
    __shared__ float red[4];
    __shared__ float red2[4];
    if (lane == 0) red[wave] = m;
    __syncthreads();
    m = fmaxf(fmaxf(red[0], red[1]), fmaxf(red[2], red[3]));
    float sum = 0.f;
#pragma unroll
    for (int i = 0; i < 8; ++i) { vals[i] = expf(vals[i] - m); sum += vals[i]; }
#pragma unroll
    for (int s = 1; s < 64; s <<= 1) sum += __shfl_xor(sum, s);
    if (lane == 0) red2[wave] = sum;
    __syncthreads();
    sum = red2[0] + red2[1] + red2[2] + red2[3];
    float inv = 1.0f / sum;
#pragma unroll
    for (int i = 0; i < 8; ++i) out[(size_t)b * T + tid + 256 * i] = vals[i] * inv;
}

extern "C" void kernel_launch(void* const* d_in, const int* in_sizes, int n_in,
                              void* d_out, int out_size, void* d_ws, size_t ws_size,
                              hipStream_t stream) {
    (void)in_sizes; (void)n_in; (void)out_size; (void)ws_size;
    const float* hidden = (const float*)d_in[0];   // [1,B,H]
    const float* enc    = (const float*)d_in[1];   // [B,T,H]
    const float* W      = (const float*)d_in[2];   // [H,2H]
    const float* bias   = (const float*)d_in[3];   // [H]
    const float* v      = (const float*)d_in[4];   // [H]
    float* out = (float*)d_out;                    // [B,1,T]

    unsigned short* Wp = (unsigned short*)d_ws;                              // 2 MB
    float* hp = (float*)((char*)d_ws + 2 * 1024 * 1024);                     // 128 KB
    float* sc = (float*)((char*)d_ws + 2 * 1024 * 1024 + 128 * 1024);        // 1 MB (4 partials)

    prep_w_kernel<<<dim3(512), dim3(256), 0, stream>>>(W, Wp);
    prep_hp_kernel<<<dim3(8, B), dim3(128), 0, stream>>>(hidden, W, bias, hp);
    energy_kernel<<<dim3(T / BM, NCOLT, B), dim3(512), 0, stream>>>(enc, hp, v, Wp, sc);
    softmax_kernel<<<dim3(B), dim3(256), 0, stream>>>(sc, out);
}